// Round 2
// 1015.804 us; speedup vs baseline: 1.0088x; 1.0088x over previous
//
#include <hip/hip_runtime.h>
#include <stdint.h>
#include <math.h>

#define NN 12288
#define DD 128
#define KTOP 31
#define TILE 128
#define GB (NN / TILE)   // 96
#define TCAND 64         // R4-verified margin: candidate set >= top-64 by bf16 key
#define CCAP 128         // compaction capacity (bucket-inclusive superset of top-64)
#define FUSE_ROWS 6144   // rows emitted inside scan (lower half of d_out; simmat lives in upper half)

typedef __attribute__((ext_vector_type(8))) short bf16x8;
typedef __attribute__((ext_vector_type(4))) float f32x4;

__device__ __forceinline__ unsigned short f2bf(float x) {  // RNE, no NaN in our data
  unsigned int u = __float_as_uint(x);
  u += 0x7fffu + ((u >> 16) & 1u);
  return (unsigned short)(u >> 16);
}

// med3(p, L[i], L[i+1]) == the sorted-ladder insert step (verified: p<=L[i] -> L[i];
// L[i]<p<=L[i+1] -> p; p>L[i+1] -> L[i+1])
__device__ __forceinline__ unsigned umed3(unsigned a, unsigned b, unsigned c) {
  unsigned d;
  asm("v_med3_u32 %0, %1, %2, %3" : "=v"(d) : "v"(a), "v"(b), "v"(c));
  return d;
}

// ---------------- Kernel 0: transpose W1,W2 so mlp reads are coalesced ----------------
__global__ __launch_bounds__(128)
void wtrans_kernel(const float* __restrict__ W1, const float* __restrict__ W2,
                   float* __restrict__ W1T, float* __restrict__ W2T) {
  const int r = blockIdx.x, c = threadIdx.x;
  W1T[(size_t)c * DD + r] = W1[(size_t)r * DD + c];
  W2T[(size_t)c * DD + r] = W2[(size_t)r * DD + c];
}

// ---------------- Kernel 1: MLP (Linear-ReLU-Linear) + L2 normalize, fp64; taps fp64 + bf16 ----------------
// W accessed via W^T: at step k, lane t reads W1T[k*DD+t] -> fully coalesced (was a
// 64-line/wave gather). LDS feat reads vectorized to double2 (b128). FMA order over k
// is unchanged (k, then k+1) -> bit-identical results.
__global__ __launch_bounds__(128)
void mlp_norm_kernel(const float* __restrict__ feat,
                     const float* __restrict__ W1T, const float* __restrict__ b1,
                     const float* __restrict__ W2T, const float* __restrict__ b2,
                     double* __restrict__ hn64, unsigned short* __restrict__ hnb) {
  __shared__ double bufA[8][DD];
  __shared__ double bufB[8][DD];
  __shared__ double mnorm[8];
  const int t = threadIdx.x;
  const int row0 = blockIdx.x * 8;

  #pragma unroll
  for (int rr = 0; rr < 8; ++rr)
    bufA[rr][t] = (double)feat[(size_t)(row0 + rr) * DD + t];
  __syncthreads();

  {
    double acc[8] = {0,0,0,0,0,0,0,0};
    for (int k = 0; k < DD; k += 2) {
      double w0 = (double)W1T[(size_t)k * DD + t];
      double w1 = (double)W1T[(size_t)(k + 1) * DD + t];
      #pragma unroll
      for (int rr = 0; rr < 8; ++rr) {
        double2 a2 = *(const double2*)(&bufA[rr][k]);
        acc[rr] = fma(w0, a2.x, acc[rr]);
        acc[rr] = fma(w1, a2.y, acc[rr]);
      }
    }
    double bb = (double)b1[t];
    #pragma unroll
    for (int rr = 0; rr < 8; ++rr)
      bufB[rr][t] = fmax(acc[rr] + bb, 0.0);
  }
  __syncthreads();
  {
    double acc[8] = {0,0,0,0,0,0,0,0};
    for (int k = 0; k < DD; k += 2) {
      double w0 = (double)W2T[(size_t)k * DD + t];
      double w1 = (double)W2T[(size_t)(k + 1) * DD + t];
      #pragma unroll
      for (int rr = 0; rr < 8; ++rr) {
        double2 a2 = *(const double2*)(&bufB[rr][k]);
        acc[rr] = fma(w0, a2.x, acc[rr]);
        acc[rr] = fma(w1, a2.y, acc[rr]);
      }
    }
    double bb = (double)b2[t];
    #pragma unroll
    for (int rr = 0; rr < 8; ++rr)
      bufA[rr][t] = acc[rr] + bb;
  }
  __syncthreads();

  const int lane = t & 63;
  const int w = t >> 6;
  #pragma unroll
  for (int r2 = 0; r2 < 4; ++r2) {
    int rr = w * 4 + r2;
    double x0 = bufA[rr][lane];
    double x1 = bufA[rr][lane + 64];
    double s = x0 * x0 + x1 * x1;
    #pragma unroll
    for (int d = 1; d < 64; d <<= 1)
      s += __shfl_xor(s, d);
    if (lane == 0) mnorm[rr] = fmax(sqrt(s), 1e-12);
  }
  __syncthreads();
  #pragma unroll
  for (int rr = 0; rr < 8; ++rr) {
    double v = bufA[rr][t] / mnorm[rr];
    hn64[(size_t)(row0 + rr) * DD + t] = v;
    hnb[(size_t)(row0 + rr) * DD + t] = f2bf((float)v);
  }
}

// ---------------- Kernel 2: bf16 MFMA GEMM, sim = hn*hn^T, bf16 out to scratch ----------------
__device__ __forceinline__ int lunit(int c, int r, int q) {
  return c * 512 + r * 4 + ((q + (r >> 1)) & 3);
}

__global__ __launch_bounds__(256)
void gemm_kernel(const unsigned short* __restrict__ hnb,
                 unsigned short* __restrict__ simmat) {
  __shared__ __attribute__((aligned(16))) unsigned short At[16384];  // 32 KB
  __shared__ __attribute__((aligned(16))) unsigned short Bt[16384];  // 32 KB
  const int t = threadIdx.x;
  const int lane = t & 63;
  const int wv = t >> 6;
  const int bi = blockIdx.x / GB, bj = blockIdx.x % GB;
  const int r0 = bi * TILE, c0 = bj * TILE;

  #pragma unroll
  for (int i = 0; i < 8; ++i) {
    int u = i * 256 + t;
    int c = u >> 9, r = (u >> 2) & 127, g = u & 3;
    int q = (g - (r >> 1)) & 3;
    uint4 v = *(const uint4*)(hnb + (size_t)(r0 + r) * DD + c * 32 + q * 8);
    *(uint4*)(At + u * 8) = v;
  }
  #pragma unroll
  for (int i = 0; i < 8; ++i) {
    int u = i * 256 + t;
    int c = u >> 9, r = (u >> 2) & 127, g = u & 3;
    int q = (g - (r >> 1)) & 3;
    uint4 v = *(const uint4*)(hnb + (size_t)(c0 + r) * DD + c * 32 + q * 8);
    *(uint4*)(Bt + u * 8) = v;
  }
  __syncthreads();

  const int wr = (wv >> 1) * 64;
  const int wc = (wv & 1) * 64;
  const int m = lane & 15, quad = lane >> 4;

  f32x4 acc[4][4] = {};
  #pragma unroll
  for (int kc = 0; kc < 4; ++kc) {
    bf16x8 a[4], b[4];
    #pragma unroll
    for (int i = 0; i < 4; ++i)
      a[i] = *(const bf16x8*)(At + lunit(kc, wr + i * 16 + m, quad) * 8);
    #pragma unroll
    for (int j = 0; j < 4; ++j)
      b[j] = *(const bf16x8*)(Bt + lunit(kc, wc + j * 16 + m, quad) * 8);
    #pragma unroll
    for (int i = 0; i < 4; ++i)
      #pragma unroll
      for (int j = 0; j < 4; ++j)
        acc[i][j] = __builtin_amdgcn_mfma_f32_16x16x32_bf16(a[i], b[j], acc[i][j], 0, 0, 0);
  }

  const bool evenl = !(lane & 1);
  #pragma unroll
  for (int i = 0; i < 4; ++i)
    #pragma unroll
    for (int j = 0; j < 4; ++j)
      #pragma unroll
      for (int r = 0; r < 4; ++r) {
        float v = acc[i][j][r];
        float v2 = __shfl_xor(v, 1);
        if (evenl) {
          unsigned int pk = (unsigned int)f2bf(v) | ((unsigned int)f2bf(v2) << 16);
          int R = r0 + wr + i * 16 + quad * 4 + r;
          int C = c0 + wc + j * 16 + m;
          *(unsigned int*)(simmat + (size_t)R * NN + C) = pk;
        }
      }
}

// ---------------- Kernel 3: lane-private top-8 scan + threshold(>=64) select + fp64 rescore ----------------
// Phase 1 insert is a branchless v_med3_u32 ladder (identical math to the old
// select ladder; the guard branch was wave-taken ~93% of the time anyway).
// Rows < FUSE_ROWS additionally emit their own output row (zeros + scatter) at the
// end: output lower half [0, 302MB) is disjoint from simmat (upper half of d_out),
// so no scan wave can clobber another's unread simmat row.
#define PINS(P) { \
  const unsigned p_ = (P); \
  _Pragma("unroll") \
  for (int i_ = 0; i_ < 7; ++i_) \
    L[i_] = umed3(p_, L[i_], L[i_ + 1]); \
  L[7] = L[7] > p_ ? L[7] : p_; }

__global__ __launch_bounds__(256)
void scan_rescore_kernel(const unsigned short* __restrict__ simmat,
                         const double* __restrict__ hn64,
                         float* __restrict__ resval, int* __restrict__ rescol,
                         float* __restrict__ out) {
  __shared__ unsigned scand[4][CCAP];
  const int t = threadIdx.x, lane = t & 63, wv = t >> 6;
  const int row = blockIdx.x * 4 + wv;
  const unsigned short* srow = simmat + (size_t)row * NN;

  // phase 1: lane-private sorted top-8 (packed: s16<<16 | col14), branchless med3
  unsigned L[8] = {0, 0, 0, 0, 0, 0, 0, 0};
  for (int it = 0; it < NN / 512; ++it) {
    uint4 pk = *(const uint4*)(srow + it * 512 + lane * 8);
    const unsigned cb = it * 512 + lane * 8;
    unsigned wds[4] = {pk.x, pk.y, pk.z, pk.w};
    #pragma unroll
    for (int q = 0; q < 4; ++q) {
      unsigned b0 = wds[q] & 0xFFFFu, b1v = wds[q] >> 16;
      unsigned s0 = (b0 & 0x8000u) ? 0u : b0;   // clamp negatives to rank 0
      unsigned s1 = (b1v & 0x8000u) ? 0u : b1v;
      unsigned p0 = (s0 << 16) | (cb + 2 * q);
      unsigned p1 = (s1 << 16) | (cb + 2 * q + 1);
      PINS(p0)
      PINS(p1)
    }
  }

  // phase 2: binary search largest thr with wave-count(s >= thr) >= TCAND
  unsigned lo = 0, hi = 0xFFFFu;
  while (lo < hi) {
    unsigned mid = (lo + hi + 1) >> 1;
    int c = 0;
    #pragma unroll
    for (int i = 0; i < 8; ++i) c += (int)((L[i] >> 16) >= mid);
    #pragma unroll
    for (int d = 1; d < 64; d <<= 1) c += __shfl_xor(c, d);
    if (c >= TCAND) lo = mid; else hi = mid - 1;
  }
  const unsigned thr = lo;

  // compaction: exclusive prefix over per-lane qualifying counts, cap CCAP
  int cl = 0;
  #pragma unroll
  for (int i = 0; i < 8; ++i) cl += (int)((L[i] >> 16) >= thr);
  int pre = cl;
  #pragma unroll
  for (int d = 1; d < 64; d <<= 1) {
    int y = __shfl_up(pre, d);
    if (lane >= d) pre += y;
  }
  const int total = __shfl(pre, 63);
  const int nc = total < CCAP ? total : CCAP;
  int slot = pre - cl;
  #pragma unroll
  for (int i = 0; i < 8; ++i) {
    if ((L[i] >> 16) >= thr) {
      if (slot < CCAP) scand[wv][slot] = L[i];
      ++slot;
    }
  }
  __syncthreads();

  // phase 3: fp64 rescore, candidates lane and lane+64 (verified R2 math)
  const double* arow = hn64 + (size_t)row * DD;
  double rv0 = -1.0e300, rv1 = -1.0e300;
  int rc0 = 0x7fffffff, rc1 = 0x7fffffff;
  if (lane < nc) {
    const int col = (int)(scand[wv][lane] & 0xFFFFu);
    const double* brow = hn64 + (size_t)col * DD;
    double acc = 0.0;
    for (int k = 0; k < DD; k += 2) {
      double2 a2 = *(const double2*)(arow + k);
      double2 b2 = *(const double2*)(brow + k);
      acc = fma(a2.x, b2.x, acc);
      acc = fma(a2.y, b2.y, acc);
    }
    rv0 = acc; rc0 = col;
  }
  if (lane + 64 < nc) {
    const int col = (int)(scand[wv][lane + 64] & 0xFFFFu);
    const double* brow = hn64 + (size_t)col * DD;
    double acc = 0.0;
    for (int k = 0; k < DD; k += 2) {
      double2 a2 = *(const double2*)(arow + k);
      double2 b2 = *(const double2*)(brow + k);
      acc = fma(a2.x, b2.x, acc);
      acc = fma(a2.y, b2.y, acc);
    }
    rv1 = acc; rc1 = col;
  }

  // phase 4: extract exact top-31 from 2 regs x 64 lanes, ties (val desc, col asc)
  const bool fuse = (row < FUSE_ROWS);
  float fkv = 0.0f; int fkc = 0;
  for (int itk = 0; itk < KTOP; ++itk) {
    bool f = (rv0 > rv1) || (rv0 == rv1 && rc0 < rc1);
    double bv = f ? rv0 : rv1;
    int bc = f ? rc0 : rc1;
    #pragma unroll
    for (int d = 1; d < 64; d <<= 1) {
      double ov = __shfl_xor(bv, d);
      int    oc = __shfl_xor(bc, d);
      bool tk = (ov > bv) || (ov == bv && oc < bc);
      bv = tk ? ov : bv;
      bc = tk ? oc : bc;
    }
    if (lane == itk) {
      float ovv = (float)fmax(bv, 0.0);
      fkv = ovv; fkc = bc;
      if (!fuse) {
        resval[(size_t)row * KTOP + itk] = ovv;
        rescol[(size_t)row * KTOP + itk] = bc;
      }
    }
    if (rv0 == bv && rc0 == bc) rv0 = -1.0e300;
    else if (rv1 == bv && rc1 == bc) rv1 = -1.0e300;
  }

  // phase 5 (rows < FUSE_ROWS): fused emit — nontemporal zeros + scatter.
  if (fuse) {
    f32x4* orow = (f32x4*)(out + (size_t)row * NN);
    const f32x4 z = {0.0f, 0.0f, 0.0f, 0.0f};
    #pragma unroll
    for (int i = 0; i < NN / 4 / 64; ++i)
      __builtin_nontemporal_store(z, &orow[i * 64 + lane]);
    __syncthreads();   // drain zero stores before scatter overwrites
    if (lane < KTOP) out[(size_t)row * NN + fkc] = fkv;
  }
}

// ---------------- Kernel 4: emit remaining rows (overlay the simmat upper half) ----------------
__global__ __launch_bounds__(256)
void emit_kernel(const float* __restrict__ resval, const int* __restrict__ rescol,
                 float* __restrict__ out) {
  const int row = blockIdx.x + FUSE_ROWS, t = threadIdx.x;
  float v = 0.0f; int c = 0;
  if (t < KTOP) {
    v = resval[(size_t)row * KTOP + t];
    c = rescol[(size_t)row * KTOP + t];
  }
  f32x4* orow = (f32x4*)(out + (size_t)row * NN);
  const f32x4 z = {0.0f, 0.0f, 0.0f, 0.0f};
  #pragma unroll
  for (int i = 0; i < NN / 4 / 256; ++i)
    __builtin_nontemporal_store(z, &orow[i * 256 + t]);
  __syncthreads();   // zeros drained before scatter overwrites
  if (t < KTOP) out[(size_t)row * NN + c] = v;
}

extern "C" void kernel_launch(void* const* d_in, const int* in_sizes, int n_in,
                              void* d_out, int out_size, void* d_ws, size_t ws_size,
                              hipStream_t stream) {
  const float* feat = (const float*)d_in[0];
  const float* W1 = (const float*)d_in[1];
  const float* b1 = (const float*)d_in[2];
  const float* W2 = (const float*)d_in[3];
  const float* b2 = (const float*)d_in[4];
  float* out = (float*)d_out;

  // ws: hn64 (12.6 MB) | hnb bf16 (3.1 MB) | resval (1.5 MB) | rescol (1.5 MB) | W1T,W2T (128 KB)
  double* hn64 = (double*)d_ws;
  unsigned short* hnb = (unsigned short*)(hn64 + (size_t)NN * DD);
  float* resval = (float*)(hnb + (size_t)NN * DD);
  int* rescol = (int*)(resval + (size_t)NN * KTOP);
  float* W1T = (float*)(rescol + (size_t)NN * KTOP);
  float* W2T = W1T + DD * DD;

  // simmat lives in the UPPER half of d_out (exactly out_size/2 = 302 MB), so
  // output rows [0, FUSE_ROWS) — the lower half — never alias it and can be emitted
  // inside scan_rescore. Rows >= FUSE_ROWS are emitted after scan completes.
  unsigned short* simmat = (unsigned short*)((char*)d_out + (size_t)NN * NN * 2);

  wtrans_kernel<<<DD, DD, 0, stream>>>(W1, W2, W1T, W2T);
  mlp_norm_kernel<<<NN / 8, 128, 0, stream>>>(feat, W1T, b1, W2T, b2, hn64, hnb);
  gemm_kernel<<<GB * GB, 256, 0, stream>>>(hnb, simmat);
  scan_rescore_kernel<<<NN / 4, 256, 0, stream>>>(simmat, hn64, resval, rescol, out);
  emit_kernel<<<NN - FUSE_ROWS, 256, 0, stream>>>(resval, rescol, out);
}

// Round 3
// 948.294 us; speedup vs baseline: 1.0806x; 1.0712x over previous
//
#include <hip/hip_runtime.h>
#include <stdint.h>
#include <math.h>

#define NN 12288
#define DD 128
#define KTOP 31
#define TILE 128
#define GB (NN / TILE)   // 96
#define TCAND 64         // R4-verified margin: candidate set >= top-64 by bf16 key
#define CCAP 128         // compaction capacity (bucket-inclusive superset of top-64)
#define FUSE_ROWS 6144   // rows emitted inside scan (lower half of d_out; simmat lives in upper half)

typedef __attribute__((ext_vector_type(8))) short bf16x8;
typedef __attribute__((ext_vector_type(4))) float f32x4;

__device__ __forceinline__ unsigned short f2bf(float x) {  // RNE, no NaN in our data
  unsigned int u = __float_as_uint(x);
  u += 0x7fffu + ((u >> 16) & 1u);
  return (unsigned short)(u >> 16);
}

// med3(p, L[i], L[i+1]) == the sorted-ladder insert step (verified: p<=L[i] -> L[i];
// L[i]<p<=L[i+1] -> p; p>L[i+1] -> L[i+1])
__device__ __forceinline__ unsigned umed3(unsigned a, unsigned b, unsigned c) {
  unsigned d;
  asm("v_med3_u32 %0, %1, %2, %3" : "=v"(d) : "v"(a), "v"(b), "v"(c));
  return d;
}

// ---------------- Kernel 0: transpose W1,W2 so mlp reads are coalesced ----------------
__global__ __launch_bounds__(128)
void wtrans_kernel(const float* __restrict__ W1, const float* __restrict__ W2,
                   float* __restrict__ W1T, float* __restrict__ W2T) {
  const int r = blockIdx.x, c = threadIdx.x;
  W1T[(size_t)c * DD + r] = W1[(size_t)r * DD + c];
  W2T[(size_t)c * DD + r] = W2[(size_t)r * DD + c];
}

// ---------------- Kernel 1: MLP (Linear-ReLU-Linear) + L2 normalize, fp64; taps fp64 + bf16 ----------------
__global__ __launch_bounds__(128)
void mlp_norm_kernel(const float* __restrict__ feat,
                     const float* __restrict__ W1T, const float* __restrict__ b1,
                     const float* __restrict__ W2T, const float* __restrict__ b2,
                     double* __restrict__ hn64, unsigned short* __restrict__ hnb) {
  __shared__ double bufA[8][DD];
  __shared__ double bufB[8][DD];
  __shared__ double mnorm[8];
  const int t = threadIdx.x;
  const int row0 = blockIdx.x * 8;

  #pragma unroll
  for (int rr = 0; rr < 8; ++rr)
    bufA[rr][t] = (double)feat[(size_t)(row0 + rr) * DD + t];
  __syncthreads();

  {
    double acc[8] = {0,0,0,0,0,0,0,0};
    for (int k = 0; k < DD; k += 2) {
      double w0 = (double)W1T[(size_t)k * DD + t];
      double w1 = (double)W1T[(size_t)(k + 1) * DD + t];
      #pragma unroll
      for (int rr = 0; rr < 8; ++rr) {
        double2 a2 = *(const double2*)(&bufA[rr][k]);
        acc[rr] = fma(w0, a2.x, acc[rr]);
        acc[rr] = fma(w1, a2.y, acc[rr]);
      }
    }
    double bb = (double)b1[t];
    #pragma unroll
    for (int rr = 0; rr < 8; ++rr)
      bufB[rr][t] = fmax(acc[rr] + bb, 0.0);
  }
  __syncthreads();
  {
    double acc[8] = {0,0,0,0,0,0,0,0};
    for (int k = 0; k < DD; k += 2) {
      double w0 = (double)W2T[(size_t)k * DD + t];
      double w1 = (double)W2T[(size_t)(k + 1) * DD + t];
      #pragma unroll
      for (int rr = 0; rr < 8; ++rr) {
        double2 a2 = *(const double2*)(&bufB[rr][k]);
        acc[rr] = fma(w0, a2.x, acc[rr]);
        acc[rr] = fma(w1, a2.y, acc[rr]);
      }
    }
    double bb = (double)b2[t];
    #pragma unroll
    for (int rr = 0; rr < 8; ++rr)
      bufA[rr][t] = acc[rr] + bb;
  }
  __syncthreads();

  const int lane = t & 63;
  const int w = t >> 6;
  #pragma unroll
  for (int r2 = 0; r2 < 4; ++r2) {
    int rr = w * 4 + r2;
    double x0 = bufA[rr][lane];
    double x1 = bufA[rr][lane + 64];
    double s = x0 * x0 + x1 * x1;
    #pragma unroll
    for (int d = 1; d < 64; d <<= 1)
      s += __shfl_xor(s, d);
    if (lane == 0) mnorm[rr] = fmax(sqrt(s), 1e-12);
  }
  __syncthreads();
  #pragma unroll
  for (int rr = 0; rr < 8; ++rr) {
    double v = bufA[rr][t] / mnorm[rr];
    hn64[(size_t)(row0 + rr) * DD + t] = v;
    hnb[(size_t)(row0 + rr) * DD + t] = f2bf((float)v);
  }
}

// ---------------- Kernel 2: bf16 MFMA GEMM, sim = hn*hn^T, bf16 out to scratch ----------------
__device__ __forceinline__ int lunit(int c, int r, int q) {
  return c * 512 + r * 4 + ((q + (r >> 1)) & 3);
}

__global__ __launch_bounds__(256)
void gemm_kernel(const unsigned short* __restrict__ hnb,
                 unsigned short* __restrict__ simmat) {
  __shared__ __attribute__((aligned(16))) unsigned short At[16384];  // 32 KB
  __shared__ __attribute__((aligned(16))) unsigned short Bt[16384];  // 32 KB
  const int t = threadIdx.x;
  const int lane = t & 63;
  const int wv = t >> 6;
  const int bi = blockIdx.x / GB, bj = blockIdx.x % GB;
  const int r0 = bi * TILE, c0 = bj * TILE;

  #pragma unroll
  for (int i = 0; i < 8; ++i) {
    int u = i * 256 + t;
    int c = u >> 9, r = (u >> 2) & 127, g = u & 3;
    int q = (g - (r >> 1)) & 3;
    uint4 v = *(const uint4*)(hnb + (size_t)(r0 + r) * DD + c * 32 + q * 8);
    *(uint4*)(At + u * 8) = v;
  }
  #pragma unroll
  for (int i = 0; i < 8; ++i) {
    int u = i * 256 + t;
    int c = u >> 9, r = (u >> 2) & 127, g = u & 3;
    int q = (g - (r >> 1)) & 3;
    uint4 v = *(const uint4*)(hnb + (size_t)(c0 + r) * DD + c * 32 + q * 8);
    *(uint4*)(Bt + u * 8) = v;
  }
  __syncthreads();

  const int wr = (wv >> 1) * 64;
  const int wc = (wv & 1) * 64;
  const int m = lane & 15, quad = lane >> 4;

  f32x4 acc[4][4] = {};
  #pragma unroll
  for (int kc = 0; kc < 4; ++kc) {
    bf16x8 a[4], b[4];
    #pragma unroll
    for (int i = 0; i < 4; ++i)
      a[i] = *(const bf16x8*)(At + lunit(kc, wr + i * 16 + m, quad) * 8);
    #pragma unroll
    for (int j = 0; j < 4; ++j)
      b[j] = *(const bf16x8*)(Bt + lunit(kc, wc + j * 16 + m, quad) * 8);
    #pragma unroll
    for (int i = 0; i < 4; ++i)
      #pragma unroll
      for (int j = 0; j < 4; ++j)
        acc[i][j] = __builtin_amdgcn_mfma_f32_16x16x32_bf16(a[i], b[j], acc[i][j], 0, 0, 0);
  }

  const bool evenl = !(lane & 1);
  #pragma unroll
  for (int i = 0; i < 4; ++i)
    #pragma unroll
    for (int j = 0; j < 4; ++j)
      #pragma unroll
      for (int r = 0; r < 4; ++r) {
        float v = acc[i][j][r];
        float v2 = __shfl_xor(v, 1);
        if (evenl) {
          unsigned int pk = (unsigned int)f2bf(v) | ((unsigned int)f2bf(v2) << 16);
          int R = r0 + wr + i * 16 + quad * 4 + r;
          int C = c0 + wc + j * 16 + m;
          *(unsigned int*)(simmat + (size_t)R * NN + C) = pk;
        }
      }
}

// ---------------- Kernel 3: lane-private top-8 scan + threshold(>=64) select + fp64 rescore ----------------
// Phase 3 REWRITTEN this round: the old per-lane row-gather issued 64 distinct
// cache lines per load instruction (128 instrs/row -> ~8K line-requests/row; the
// hidden serialization elephant). New: candidate-PAIR processing. Half-wave h
// owns candidate 2g+h; its 32 lanes read 4 consecutive doubles (2x double2,
// contiguous 512 B per half-wave -> 8 lines/instr), 4 FMAs, 5-step half-wave
// shfl_xor reduce; lane 0 of each half parks the dot in LDS. Loop runs
// ceil(nc/2) groups (~32-45) instead of fixed 128 predicated passes.
// FMA order change -> fp64 delta ~1e-16 (vs ~1e-3 rank gaps): zero risk.
#define PINS(P) { \
  const unsigned p_ = (P); \
  _Pragma("unroll") \
  for (int i_ = 0; i_ < 7; ++i_) \
    L[i_] = umed3(p_, L[i_], L[i_ + 1]); \
  L[7] = L[7] > p_ ? L[7] : p_; }

__global__ __launch_bounds__(256)
void scan_rescore_kernel(const unsigned short* __restrict__ simmat,
                         const double* __restrict__ hn64,
                         float* __restrict__ resval, int* __restrict__ rescol,
                         float* __restrict__ out) {
  __shared__ unsigned scand[4][CCAP];
  __shared__ double cres[4][CCAP];
  const int t = threadIdx.x, lane = t & 63, wv = t >> 6;
  const int row = blockIdx.x * 4 + wv;
  const unsigned short* srow = simmat + (size_t)row * NN;

  // phase 1: lane-private sorted top-8 (packed: s16<<16 | col14), branchless med3
  unsigned L[8] = {0, 0, 0, 0, 0, 0, 0, 0};
  for (int it = 0; it < NN / 512; ++it) {
    uint4 pk = *(const uint4*)(srow + it * 512 + lane * 8);
    const unsigned cb = it * 512 + lane * 8;
    unsigned wds[4] = {pk.x, pk.y, pk.z, pk.w};
    #pragma unroll
    for (int q = 0; q < 4; ++q) {
      unsigned b0 = wds[q] & 0xFFFFu, b1v = wds[q] >> 16;
      unsigned s0 = (b0 & 0x8000u) ? 0u : b0;   // clamp negatives to rank 0
      unsigned s1 = (b1v & 0x8000u) ? 0u : b1v;
      unsigned p0 = (s0 << 16) | (cb + 2 * q);
      unsigned p1 = (s1 << 16) | (cb + 2 * q + 1);
      PINS(p0)
      PINS(p1)
    }
  }

  // phase 2: binary search largest thr with wave-count(s >= thr) >= TCAND
  unsigned lo = 0, hi = 0xFFFFu;
  while (lo < hi) {
    unsigned mid = (lo + hi + 1) >> 1;
    int c = 0;
    #pragma unroll
    for (int i = 0; i < 8; ++i) c += (int)((L[i] >> 16) >= mid);
    #pragma unroll
    for (int d = 1; d < 64; d <<= 1) c += __shfl_xor(c, d);
    if (c >= TCAND) lo = mid; else hi = mid - 1;
  }
  const unsigned thr = lo;

  // compaction: exclusive prefix over per-lane qualifying counts, cap CCAP
  int cl = 0;
  #pragma unroll
  for (int i = 0; i < 8; ++i) cl += (int)((L[i] >> 16) >= thr);
  int pre = cl;
  #pragma unroll
  for (int d = 1; d < 64; d <<= 1) {
    int y = __shfl_up(pre, d);
    if (lane >= d) pre += y;
  }
  const int total = __shfl(pre, 63);
  const int nc = total < CCAP ? total : CCAP;
  int slot = pre - cl;
  #pragma unroll
  for (int i = 0; i < 8; ++i) {
    if ((L[i] >> 16) >= thr) {
      if (slot < CCAP) scand[wv][slot] = L[i];
      ++slot;
    }
  }
  __syncthreads();

  // phase 3: coalesced pair-wise fp64 rescore
  const double* arow = hn64 + (size_t)row * DD;
  const int hl = lane >> 5;          // half-wave index (candidate 2g+hl)
  const int kl = (lane & 31) * 4;    // this lane's 4-double chunk
  const double a0 = arow[kl], a1 = arow[kl + 1], a2 = arow[kl + 2], a3 = arow[kl + 3];
  const int ng = (nc + 1) >> 1;
  for (int g = 0; g < ng; ++g) {
    const int ci = 2 * g + hl;
    double partial = 0.0;
    if (ci < nc) {
      const int col = (int)(scand[wv][ci] & 0xFFFFu);
      const double* brow = hn64 + (size_t)col * DD + kl;
      double2 b01 = *(const double2*)(brow);
      double2 b23 = *(const double2*)(brow + 2);
      partial = fma(a0, b01.x, fma(a1, b01.y, fma(a2, b23.x, a3 * b23.y)));
    }
    #pragma unroll
    for (int d = 1; d < 32; d <<= 1)
      partial += __shfl_xor(partial, d);
    if ((lane & 31) == 0 && ci < nc) cres[wv][ci] = partial;
  }
  // same-wave LDS producer->consumer: compiler inserts lgkmcnt; no barrier needed
  double rv0 = -1.0e300, rv1 = -1.0e300;
  int rc0 = 0x7fffffff, rc1 = 0x7fffffff;
  if (lane < nc) {
    rv0 = cres[wv][lane];
    rc0 = (int)(scand[wv][lane] & 0xFFFFu);
  }
  if (lane + 64 < nc) {
    rv1 = cres[wv][lane + 64];
    rc1 = (int)(scand[wv][lane + 64] & 0xFFFFu);
  }

  // phase 4: extract exact top-31 from 2 regs x 64 lanes, ties (val desc, col asc)
  const bool fuse = (row < FUSE_ROWS);
  float fkv = 0.0f; int fkc = 0;
  for (int itk = 0; itk < KTOP; ++itk) {
    bool f = (rv0 > rv1) || (rv0 == rv1 && rc0 < rc1);
    double bv = f ? rv0 : rv1;
    int bc = f ? rc0 : rc1;
    #pragma unroll
    for (int d = 1; d < 64; d <<= 1) {
      double ov = __shfl_xor(bv, d);
      int    oc = __shfl_xor(bc, d);
      bool tk = (ov > bv) || (ov == bv && oc < bc);
      bv = tk ? ov : bv;
      bc = tk ? oc : bc;
    }
    if (lane == itk) {
      float ovv = (float)fmax(bv, 0.0);
      fkv = ovv; fkc = bc;
      if (!fuse) {
        resval[(size_t)row * KTOP + itk] = ovv;
        rescol[(size_t)row * KTOP + itk] = bc;
      }
    }
    if (rv0 == bv && rc0 == bc) rv0 = -1.0e300;
    else if (rv1 == bv && rc1 == bc) rv1 = -1.0e300;
  }

  // phase 5 (rows < FUSE_ROWS): fused emit — nontemporal zeros + scatter.
  if (fuse) {
    f32x4* orow = (f32x4*)(out + (size_t)row * NN);
    const f32x4 z = {0.0f, 0.0f, 0.0f, 0.0f};
    #pragma unroll
    for (int i = 0; i < NN / 4 / 64; ++i)
      __builtin_nontemporal_store(z, &orow[i * 64 + lane]);
    __syncthreads();   // drain zero stores before scatter overwrites
    if (lane < KTOP) out[(size_t)row * NN + fkc] = fkv;
  }
}

// ---------------- Kernel 4: emit remaining rows (overlay the simmat upper half) ----------------
__global__ __launch_bounds__(256)
void emit_kernel(const float* __restrict__ resval, const int* __restrict__ rescol,
                 float* __restrict__ out) {
  const int row = blockIdx.x + FUSE_ROWS, t = threadIdx.x;
  float v = 0.0f; int c = 0;
  if (t < KTOP) {
    v = resval[(size_t)row * KTOP + t];
    c = rescol[(size_t)row * KTOP + t];
  }
  f32x4* orow = (f32x4*)(out + (size_t)row * NN);
  const f32x4 z = {0.0f, 0.0f, 0.0f, 0.0f};
  #pragma unroll
  for (int i = 0; i < NN / 4 / 256; ++i)
    __builtin_nontemporal_store(z, &orow[i * 256 + t]);
  __syncthreads();   // zeros drained before scatter overwrites
  if (t < KTOP) out[(size_t)row * NN + c] = v;
}

extern "C" void kernel_launch(void* const* d_in, const int* in_sizes, int n_in,
                              void* d_out, int out_size, void* d_ws, size_t ws_size,
                              hipStream_t stream) {
  const float* feat = (const float*)d_in[0];
  const float* W1 = (const float*)d_in[1];
  const float* b1 = (const float*)d_in[2];
  const float* W2 = (const float*)d_in[3];
  const float* b2 = (const float*)d_in[4];
  float* out = (float*)d_out;

  // ws: hn64 (12.6 MB) | hnb bf16 (3.1 MB) | resval (1.5 MB) | rescol (1.5 MB) | W1T,W2T (128 KB)
  double* hn64 = (double*)d_ws;
  unsigned short* hnb = (unsigned short*)(hn64 + (size_t)NN * DD);
  float* resval = (float*)(hnb + (size_t)NN * DD);
  int* rescol = (int*)(resval + (size_t)NN * KTOP);
  float* W1T = (float*)(rescol + (size_t)NN * KTOP);
  float* W2T = W1T + DD * DD;

  // simmat lives in the UPPER half of d_out (exactly out_size/2 = 302 MB), so
  // output rows [0, FUSE_ROWS) — the lower half — never alias it and can be emitted
  // inside scan_rescore. Rows >= FUSE_ROWS are emitted after scan completes.
  unsigned short* simmat = (unsigned short*)((char*)d_out + (size_t)NN * NN * 2);

  wtrans_kernel<<<DD, DD, 0, stream>>>(W1, W2, W1T, W2T);
  mlp_norm_kernel<<<NN / 8, 128, 0, stream>>>(feat, W1T, b1, W2T, b2, hn64, hnb);
  gemm_kernel<<<GB * GB, 256, 0, stream>>>(hnb, simmat);
  scan_rescore_kernel<<<NN / 4, 256, 0, stream>>>(simmat, hn64, resval, rescol, out);
  emit_kernel<<<NN - FUSE_ROWS, 256, 0, stream>>>(resval, rescol, out);
}